// Round 18
// baseline (11858.945 us; speedup 1.0000x reference)
//
#include <hip/hip_runtime.h>
#include <hip/hip_bf16.h>
#include <math.h>

typedef unsigned short ushort_t;

#define DEV __device__ __forceinline__

DEV float bf2f(ushort_t u) {
  return __uint_as_float(((unsigned int)u) << 16);
}
DEV ushort_t f2bf(float f) {
  unsigned int x = __float_as_uint(f);
  return (ushort_t)((x + 0x7FFFu + ((x >> 16) & 1u)) >> 16);
}

// Fast exact-gelu: Abramowitz-Stegun 7.1.26 erf approx, |err| <= 1.5e-7.
DEV float gelu_f(float x) {
  float z = fabsf(x) * 0.70710678118654752f;
  float t = __builtin_amdgcn_rcpf(1.0f + 0.3275911f * z);
  float p = t * (0.254829592f +
            t * (-0.284496736f +
            t * (1.421413741f +
            t * (-1.453152027f +
            t * 1.061405429f))));
  float e = 1.0f - p * __expf(-z * z);      // erf(|x|/sqrt(2))
  float s = (x >= 0.f) ? e : -e;
  return 0.5f * x * (1.0f + s);
}

using bf16x8 = __attribute__((ext_vector_type(8))) __bf16;
using f32x4  = __attribute__((ext_vector_type(4))) float;
using u32x4  = __attribute__((ext_vector_type(4))) unsigned int;

// ---- XCD-chunked block swizzle (T1, R15 measured -7us on ff1) ----
DEV int xcd_swz(int nwg) {
  int id = blockIdx.x + gridDim.x * (blockIdx.y + gridDim.y * blockIdx.z);
  return (id & 7) * (nwg >> 3) + (id >> 3);
}

// ============================================================================
// REG-STAGED 128x128 GEMM (T14, depth 1 — R12..R15-proven; depth-2 SPILLS,
// see R11/R16: WRITE_SIZE x4-6, VGPR pinned low — do not retry).
// Single 32KB LDS, next tile in 32 VGPRs during MFMA; write-side XOR swizzle.
// Caller kernel MUST declare __launch_bounds__(256, 4) (usage ~76-90 VGPR,
// 4 blocks/CU: 4 x 32KB LDS = 128KB <= 160KB).
// C = A(MxK,rm,lda) * B^T, B(NxK,rm,ldb). K % 64 == 0.
// ============================================================================
template <typename F>
DEV void gemm_tileR(const ushort_t* A, int lda, const ushort_t* B, int ldb, int K, F&& epi) {
  __shared__ alignas(16) ushort_t As[128 * 64];
  __shared__ alignas(16) ushort_t Bs[128 * 64];
  int t = threadIdx.x;
  int lane = t & 63;
  int w = t >> 6;
  int wr = w >> 1, wc = w & 1;
  const int nk = K >> 6;
  f32x4 acc[4][4];
#pragma unroll
  for (int m = 0; m < 4; ++m)
#pragma unroll
    for (int n = 0; n < 4; ++n) acc[m][n] = (f32x4){0.f, 0.f, 0.f, 0.f};

  int aoff[4][2], boff[4][2];
#pragma unroll
  for (int m = 0; m < 4; ++m)
#pragma unroll
    for (int kk = 0; kk < 2; ++kk) {
      int ks = kk * 4 + (lane >> 4);
      aoff[m][kk] = (wr * 64 + m * 16 + (lane & 15)) * 64 + ((ks ^ (lane & 7)) * 8);
      boff[m][kk] = (wc * 64 + m * 16 + (lane & 15)) * 64 + ((ks ^ (lane & 7)) * 8);
    }

  u32x4 ra[4], rb[4];
  auto loadreg = [&](const ushort_t* g, int ld, u32x4* rr) {
#pragma unroll
    for (int r = 0; r < 4; ++r) {
      int chunk = r * 256 + t;
      rr[r] = *(const u32x4*)&g[(size_t)(chunk >> 3) * ld + (size_t)(chunk & 7) * 8];
    }
  };
  auto writelds = [&](ushort_t* lds, u32x4* rr) {
#pragma unroll
    for (int r = 0; r < 4; ++r) {
      int chunk = r * 256 + t;
      int row = chunk >> 3;
      int sl  = (chunk & 7) ^ (row & 7);          // write-side XOR swizzle
      *(u32x4*)&lds[(size_t)(row * 8 + sl) * 8] = rr[r];
    }
  };

  loadreg(A, lda, ra);
  loadreg(B, ldb, rb);

  for (int kt = 0; kt < nk; ++kt) {
    asm volatile("s_waitcnt vmcnt(0)" ::: "memory");   // tile-kt regs arrived
    __builtin_amdgcn_s_barrier();                      // prev reads done (LDS free)
    writelds(As, ra);
    writelds(Bs, rb);
    __builtin_amdgcn_s_barrier();                      // writes visible
    asm volatile("s_waitcnt lgkmcnt(0)" ::: "memory");
    __builtin_amdgcn_sched_barrier(0);
    if (kt + 1 < nk) {                                 // next tile flies under MFMA
      loadreg(A + (size_t)(kt + 1) * 64, lda, ra);
      loadreg(B + (size_t)(kt + 1) * 64, ldb, rb);
    }
#pragma unroll
    for (int kk = 0; kk < 2; ++kk) {
      bf16x8 af[4], bfr[4];
#pragma unroll
      for (int m = 0; m < 4; ++m) af[m] = *(const bf16x8*)&As[aoff[m][kk]];
#pragma unroll
      for (int n = 0; n < 4; ++n) bfr[n] = *(const bf16x8*)&Bs[boff[n][kk]];
      __builtin_amdgcn_s_setprio(1);
#pragma unroll
      for (int m = 0; m < 4; ++m)
#pragma unroll
        for (int n = 0; n < 4; ++n)
          acc[m][n] = __builtin_amdgcn_mfma_f32_16x16x32_bf16(af[m], bfr[n], acc[m][n], 0, 0, 0);
      __builtin_amdgcn_s_setprio(0);
    }
  }
  epi(wr, wc, lane, acc);
}

// ---- ff1 epilogue: paired-column packed store (w1 rows permuted by cvt_w1_kernel) ----
struct FF1Epi {
  const float* bias;
  ushort_t* out;
  int tn;
  DEV void operator()(int wr, int wc, int lane, f32x4 (&acc)[4][4]) const {
#pragma unroll
    for (int m = 0; m < 4; ++m)
#pragma unroll
      for (int q = 0; q < 2; ++q) {
        int col = wc * 64 + q * 32 + 2 * (lane & 15);      // original column (even)
        float b0 = bias[tn * 128 + col];
        float b1 = bias[tn * 128 + col + 1];
#pragma unroll
        for (int r = 0; r < 4; ++r) {
          int lr = wr * 64 + m * 16 + (lane >> 4) * 4 + r;
          float x0 = gelu_f(acc[m][2 * q][r] + b0);
          float x1 = gelu_f(acc[m][2 * q + 1][r] + b1);
          unsigned int pk = (unsigned int)f2bf(x0) | ((unsigned int)f2bf(x1) << 16);
          *(unsigned int*)&out[(size_t)lr * 2048 + col] = pk;
        }
      }
  }
};

// ---------------- FF layer 1: reg-staged tileR + XCD-chunked swizzle ----------------
__global__ __launch_bounds__(256, 4) void ff1r_kernel(
    int g0, int gn, const ushort_t* tokens, const ushort_t* levels_bf, const ushort_t* levels_pos,
    const ushort_t* w1_bf, const float* bu_b1, const float* td_b1, ushort_t* h) {
  int wid = xcd_swz(512 * gn);                 // grid = 32 x 16 x gn
  int tm = wid & 31, tn = (wid >> 5) & 15;
  int g = g0 + (wid >> 9);
  const ushort_t* A; int lda;
  if (g == 0)      { A = tokens     + (size_t)tm * 128 * 512;                              lda = 512;  }
  else if (g < 6)  { A = levels_bf  + (size_t)tm * 128 * 3072 + (size_t)(g - 1) * 512;     lda = 3072; }
  else             { A = levels_pos + (size_t)tm * 128 * 2560 + (size_t)(g - 6) * 512;     lda = 2560; }
  const ushort_t* W = w1_bf + (size_t)g * 2048 * 512 + (size_t)tn * 128 * 512;
  const float* bias = (g < 6) ? (bu_b1 + (size_t)g * 2048) : (td_b1 + (size_t)(g - 6) * 2048);
  ushort_t* out = h + ((size_t)(g - g0) * 4096 + (size_t)tm * 128) * 2048 + (size_t)tn * 128;
  FF1Epi epi{bias, out, tn};
  gemm_tileR(A, lda, W, 512, 512, epi);
}

// ---- ff2 epilogue: fused bias + f32 accumulate into levels ----
struct FF2Epi {
  const float* bias;
  float* levels;
  int tm, tn, l;
  DEV void operator()(int wr, int wc, int lane, f32x4 (&acc)[4][4]) const {
#pragma unroll
    for (int m = 0; m < 4; ++m)
#pragma unroll
      for (int n = 0; n < 4; ++n)
#pragma unroll
        for (int r = 0; r < 4; ++r) {
          int lr = wr * 64 + m * 16 + (lane >> 4) * 4 + r;
          int lc = wc * 64 + n * 16 + (lane & 15);
          int bn = tm * 128 + lr;
          int d  = tn * 128 + lc;
          size_t idx = ((size_t)bn * 6 + l) * 512 + d;
          levels[idx] += acc[m][n][r] + bias[d];
        }
  }
};

// ---------------- FF layer 2: reg-staged tileR + XCD-chunked swizzle ----------------
// RACE GUARD: one ff2 launch must never contain both group g and g+6 (both
// accumulate the SAME level l). Contiguous ranges of length <= 6 are safe.
__global__ __launch_bounds__(256, 4) void ff2r_kernel(
    int g0, int gn, const ushort_t* h, const ushort_t* w2_bf, const float* bu_b2,
    const float* td_b2, float* levels) {
  int wid = xcd_swz(128 * gn);                 // grid = 32 x 4 x gn
  int tm = wid & 31, tn = (wid >> 5) & 3;
  int g = g0 + (wid >> 7);
  const ushort_t* A = h + ((size_t)(g - g0) * 4096 + (size_t)tm * 128) * 2048;
  const ushort_t* W = w2_bf + (size_t)g * 512 * 2048 + (size_t)tn * 128 * 2048;
  int l = (g < 6) ? g : (g - 6);
  const float* bias = (g < 6) ? (bu_b2 + (size_t)g * 512) : (td_b2 + (size_t)(g - 6) * 512);
  FF2Epi epi{bias, levels, tm, tn, l};
  gemm_tileR(A, 2048, W, 2048, 2048, epi);
}

// ---- sim epilogue: inv-norm column scale + diag mask -> bf16 ----
struct SimEpi {
  const float* inv;
  ushort_t* out;
  int tm, tn;
  DEV void operator()(int wr, int wc, int lane, f32x4 (&acc)[4][4]) const {
#pragma unroll
    for (int m = 0; m < 4; ++m)
#pragma unroll
      for (int n = 0; n < 4; ++n)
#pragma unroll
        for (int r = 0; r < 4; ++r) {
          int lr = wr * 64 + m * 16 + (lane >> 4) * 4 + r;
          int lc = wc * 64 + n * 16 + (lane & 15);
          int i = tm * 128 + lr, j = tn * 128 + lc;
          float s = (i == j) ? -0.0005f : acc[m][n][r] * inv[j] * 0.044194173824159216f;
          out[(size_t)lr * 256 + lc] = f2bf(s);
        }
  }
};

// ---------------- SIM: tileR, fused inv-norm column scale + diag mask -> bf16 ----------
__global__ __launch_bounds__(256, 4) void sim_kernel(const ushort_t* levels_bf, const float* invn,
                                                     ushort_t* simattn) {
  int bl = blockIdx.z; int tm = blockIdx.x, tn = blockIdx.y;
  int b = bl / 6, l = bl % 6;
  const ushort_t* A = levels_bf + ((size_t)(b * 256 + tm * 128) * 6 + l) * 512;
  const ushort_t* B = levels_bf + ((size_t)(b * 256 + tn * 128) * 6 + l) * 512;
  const float* inv = invn + (size_t)bl * 256;
  ushort_t* out = simattn + ((size_t)bl * 256 + tm * 128) * 256 + (size_t)tn * 128;
  SimEpi epi{inv, out, tm, tn};
  gemm_tileR(A, 3072, B, 3072, 512, epi);
}

// ---- pv epilogue: f32 accumulate into levels ----
struct PvEpi {
  float* levels;
  int b, l, tm, tn;
  DEV void operator()(int wr, int wc, int lane, f32x4 (&acc)[4][4]) const {
#pragma unroll
    for (int m = 0; m < 4; ++m)
#pragma unroll
      for (int n = 0; n < 4; ++n)
#pragma unroll
        for (int r = 0; r < 4; ++r) {
          int lr = wr * 64 + m * 16 + (lane >> 4) * 4 + r;
          int lc = wc * 64 + n * 16 + (lane & 15);
          int nn = tm * 128 + lr;
          int d  = tn * 128 + lc;
          size_t idx = (((size_t)b * 256 + nn) * 6 + l) * 512 + d;
          levels[idx] += acc[m][n][r];
        }
  }
};

// ---------------- PV: tileR; levels += attn * levels_snapshot (f32) ----------------
__global__ __launch_bounds__(256, 4) void pv_kernel(const ushort_t* attn, const ushort_t* levelsT,
                                                    float* levels) {
  int bl = blockIdx.z; int tm = blockIdx.x, tn = blockIdx.y;
  int b = bl / 6, l = bl % 6;
  const ushort_t* A = attn + (size_t)bl * 256 * 256 + (size_t)tm * 128 * 256;
  const ushort_t* B = levelsT + ((size_t)bl * 512 + (size_t)tn * 128) * 256;
  PvEpi epi{levels, b, l, tm, tn};
  gemm_tileR(A, 256, B, 256, 256, epi);
}

// ---------------- softmax: one WAVE per 256-wide row (shuffle-reduce, no barriers) --------------
__global__ __launch_bounds__(256) void softmax_kernel(ushort_t* simattn) {
  int row = blockIdx.x * 4 + (threadIdx.x >> 6);
  int lane = threadIdx.x & 63;
  ushort_t* p = simattn + (size_t)row * 256 + lane * 4;
  ushort4 u = *(const ushort4*)p;
  float x0 = bf2f(u.x), x1 = bf2f(u.y), x2 = bf2f(u.z), x3 = bf2f(u.w);
  float mx = fmaxf(fmaxf(x0, x1), fmaxf(x2, x3));
#pragma unroll
  for (int off = 32; off > 0; off >>= 1) mx = fmaxf(mx, __shfl_xor(mx, off));
  float e0 = __expf(x0 - mx), e1 = __expf(x1 - mx), e2 = __expf(x2 - mx), e3 = __expf(x3 - mx);
  float s = e0 + e1 + e2 + e3;
#pragma unroll
  for (int off = 32; off > 0; off >>= 1) s += __shfl_xor(s, off);
  float r = __builtin_amdgcn_rcpf(s);
  u.x = f2bf(e0 * r); u.y = f2bf(e1 * r); u.z = f2bf(e2 * r); u.w = f2bf(e3 * r);
  *(ushort4*)p = u;
}

// ---- prep (+fused contrib scale): levels -> scaled levels, levels_bf, levels_pos, inv-norms ----
__global__ __launch_bounds__(128) void prep_kernel(float* levels, const float* pos_emb,
                                                   ushort_t* levels_bf, ushort_t* levels_pos,
                                                   float* invn, int apply) {
  int bid = blockIdx.x;           // (b*256+n)*6 + l
  int l = bid % 6;
  int bn = bid / 6;
  int n = bn & 255, b = bn >> 8;
  int t = threadIdx.x;
  float4 lv = *(const float4*)&levels[(size_t)bid * 512 + t * 4];
  if (apply) {
    float rc = (l == 5) ? (1.0f / 3.0f) : 0.25f;
    lv.x *= rc; lv.y *= rc; lv.z *= rc; lv.w *= rc;
    *(float4*)&levels[(size_t)bid * 512 + t * 4] = lv;   // write back scaled state
  }
  float ss = lv.x * lv.x + lv.y * lv.y + lv.z * lv.z + lv.w * lv.w;
#pragma unroll
  for (int off = 32; off > 0; off >>= 1) ss += __shfl_down(ss, off);
  __shared__ float s2[2];
  if ((t & 63) == 0) s2[t >> 6] = ss;
  __syncthreads();
  if (t == 0) {
    float tot = s2[0] + s2[1];
    invn[(size_t)(b * 6 + l) * 256 + n] = 1.0f / fmaxf(sqrtf(tot), 1e-12f);
  }
  ushort4 o;
  o.x = f2bf(lv.x); o.y = f2bf(lv.y); o.z = f2bf(lv.z); o.w = f2bf(lv.w);
  *(ushort4*)&levels_bf[(size_t)bid * 512 + t * 4] = o;
  if (l >= 1) {
    float4 pu = *(const float4*)&pos_emb[(size_t)n * 512 + t * 4];
    ushort4 op;
    op.x = f2bf(lv.x + pu.x);
    op.y = f2bf(lv.y + pu.y);
    op.z = f2bf(lv.z + pu.z);
    op.w = f2bf(lv.w + pu.w);
    *(ushort4*)&levels_pos[((size_t)bn * 5 + (l - 1)) * 512 + t * 4] = op;
  }
}

// ---------------- transpose: levels f32 (b,n,l,d) -> levelsT bf16 (b,l,d,n) ----------------
__global__ __launch_bounds__(256) void transpose_kernel(const float* levels, ushort_t* levelsT) {
  int bl = blockIdx.z; int b = bl / 6, l = bl % 6;
  int n0 = blockIdx.y * 64, d0 = blockIdx.x * 64;
  __shared__ ushort_t tile[64][72];
  int t = threadIdx.x;
#pragma unroll
  for (int rr = 0; rr < 2; ++rr) {
    int c = t + rr * 256;
    int r = c >> 3, c8 = (c & 7) * 8;
    const float* src = &levels[(((size_t)(b * 256 + n0 + r)) * 6 + l) * 512 + d0 + c8];
    float4 v0 = *(const float4*)src;
    float4 v1 = *(const float4*)(src + 4);
    tile[r][c8 + 0] = f2bf(v0.x); tile[r][c8 + 1] = f2bf(v0.y);
    tile[r][c8 + 2] = f2bf(v0.z); tile[r][c8 + 3] = f2bf(v0.w);
    tile[r][c8 + 4] = f2bf(v1.x); tile[r][c8 + 5] = f2bf(v1.y);
    tile[r][c8 + 6] = f2bf(v1.z); tile[r][c8 + 7] = f2bf(v1.w);
  }
  __syncthreads();
#pragma unroll
  for (int rr = 0; rr < 2; ++rr) {
    int c = t + rr * 256;
    int dr = c >> 3, n8 = (c & 7) * 8;
    ushort4 o0, o1;
    o0.x = tile[n8 + 0][dr]; o0.y = tile[n8 + 1][dr]; o0.z = tile[n8 + 2][dr]; o0.w = tile[n8 + 3][dr];
    o1.x = tile[n8 + 4][dr]; o1.y = tile[n8 + 5][dr]; o1.z = tile[n8 + 6][dr]; o1.w = tile[n8 + 7][dr];
    ushort_t* dst = &levelsT[((size_t)bl * 512 + d0 + dr) * 256 + n0 + n8];
    *(ushort4*)dst = o0;
    *(ushort4*)(dst + 4) = o1;
  }
}

// ---------------- patch embed: img(f32) -> tokens bf16 (4096 x 512) ----------------
__global__ __launch_bounds__(256) void tokens_kernel(const float* img, const float* ttw,
                                                     const float* ttb, ushort_t* tokens) {
  int token = blockIdx.x;
  int b = token >> 8, n = token & 255;
  int ph = n >> 4, pw = n & 15;
  __shared__ float patch[196];
  int t = threadIdx.x;
  if (t < 196) {
    int r = t / 14, cc = t % 14;
    patch[t] = img[(size_t)b * 50176 + (size_t)(ph * 14 + r) * 224 + pw * 14 + cc];
  }
  __syncthreads();
  float a0 = ttb[t];
  float a1 = ttb[t + 256];
  for (int k = 0; k < 196; ++k) {
    float p = patch[k];
    a0 += p * ttw[(size_t)k * 512 + t];
    a1 += p * ttw[(size_t)k * 512 + t + 256];
  }
  tokens[(size_t)token * 512 + t]       = f2bf(a0);
  tokens[(size_t)token * 512 + t + 256] = f2bf(a1);
}

// ---------------- init: broadcast init_levels(f32) -> levels f32 (d_out) ----------------
__global__ void init_kernel(const float* init_levels, float* levels) {
  size_t i4 = (size_t)blockIdx.x * 256 + threadIdx.x;
  size_t e0 = i4 * 4;
  int idx = (int)(e0 % 3072);
  *(float4*)&levels[e0] = *(const float4*)&init_levels[idx];
}

// ---------------- scale: levels *= 1/contrib[l], in place (final iteration only) ----------------
__global__ void scale_kernel(float* levels) {
  size_t i4 = (size_t)blockIdx.x * 256 + threadIdx.x;
  size_t e0 = i4 * 4;
  int l = (int)((e0 >> 9) % 6);
  float rc = (l == 5) ? (1.0f / 3.0f) : 0.25f;
  float4 a = *(const float4*)&levels[e0];
  float4 o = {a.x * rc, a.y * rc, a.z * rc, a.w * rc};
  *(float4*)&levels[e0] = o;
}

// ---------------- cvt: f32 -> bf16, 4 elems/thread (plain, for w2) ----------------
__global__ void cvt_kernel(const float* src, ushort_t* dst, int n4) {
  int i = blockIdx.x * 256 + threadIdx.x;
  if (i >= n4) return;
  float4 v = ((const float4*)src)[i];
  ushort4 o;
  o.x = f2bf(v.x); o.y = f2bf(v.y); o.z = f2bf(v.z); o.w = f2bf(v.w);
  ((ushort4*)dst)[i] = o;
}

// ---- cvt for w1: f32 -> bf16 with ROW PERMUTATION within 32-row groups ----
// staged row p = (r & ~31) | ((r&1)<<4) | ((r&31)>>1)  (rows = w1 output cols, 512-wide)
__global__ void cvt_w1_kernel(const float* src, ushort_t* dst, int nrows) {
  int i = blockIdx.x * 256 + threadIdx.x;          // one float4 (4 cols) per thread
  if (i >= nrows * 128) return;
  int row = i >> 7, k4 = (i & 127) * 4;
  int grp = row >> 11, rr = row & 2047;            // 2048 rows per group
  int p = (rr & ~31) | ((rr & 1) << 4) | ((rr & 31) >> 1);
  float4 v = *(const float4*)&src[(size_t)row * 512 + k4];
  ushort4 o;
  o.x = f2bf(v.x); o.y = f2bf(v.y); o.z = f2bf(v.z); o.w = f2bf(v.w);
  *(ushort4*)&dst[((size_t)(grp << 11) + p) * 512 + k4] = o;
}

extern "C" void kernel_launch(void* const* d_in, const int* in_sizes, int n_in,
                              void* d_out, int out_size, void* d_ws, size_t ws_size,
                              hipStream_t stream) {
  const float* img    = (const float*)d_in[0];
  const float* ttw    = (const float*)d_in[1];
  const float* ttb    = (const float*)d_in[2];
  const float* pos    = (const float*)d_in[3];
  const float* initlv = (const float*)d_in[4];
  const float* bu_w1  = (const float*)d_in[5];
  const float* bu_b1  = (const float*)d_in[6];
  const float* bu_w2  = (const float*)d_in[7];
  const float* bu_b2  = (const float*)d_in[8];
  const float* td_w1  = (const float*)d_in[9];
  const float* td_b1  = (const float*)d_in[10];
  const float* td_w2  = (const float*)d_in[11];
  const float* td_b2  = (const float*)d_in[12];

  float* levels = (float*)d_out;   // (b,n,6,512) f32 state lives in d_out

  const size_t HB = 16777216ull;   // bytes per h group (4096x2048 bf16)

  char* p = (char*)d_ws;
  auto alloc = [&](size_t bytes) { char* r = p; p += (bytes + 255) & ~(size_t)255; return r; };
  float*    invn       = (float*)alloc(24576ull * 4);
  ushort_t* tokens     = (ushort_t*)alloc(2097152ull * 2);
  ushort_t* levels_bf  = (ushort_t*)alloc(12582912ull * 2);
  ushort_t* levels_pos = (ushort_t*)alloc(10485760ull * 2);
  ushort_t* levelsT    = (ushort_t*)alloc(12582912ull * 2);
  ushort_t* simattn    = (ushort_t*)alloc(6291456ull * 2);
  ushort_t* w1_bf      = (ushort_t*)alloc(11534336ull * 2);
  ushort_t* w2_bf      = (ushort_t*)alloc(11534336ull * 2);
  size_t used = (size_t)(p - (char*)d_ws);
  if (used + HB > ws_size) return;                 // can't fit even 1-group h
  int gpp = (int)((ws_size - used) / HB);          // groups per FF pass
  if (gpp > 6) gpp = 6;                            // <=6 contiguous: no g/g+6 race
  ushort_t* h = (ushort_t*)alloc((size_t)gpp * HB);

  cvt_w1_kernel<<<6144, 256, 0, stream>>>(bu_w1, w1_bf, 12288);
  cvt_w1_kernel<<<5120, 256, 0, stream>>>(td_w1, w1_bf + 6291456ull, 10240);
  cvt_kernel<<<6144, 256, 0, stream>>>(bu_w2, w2_bf, 1572864);
  cvt_kernel<<<5120, 256, 0, stream>>>(td_w2, w2_bf + 6291456ull, 1310720);
  tokens_kernel<<<4096, 256, 0, stream>>>(img, ttw, ttb, tokens);
  init_kernel<<<12288, 256, 0, stream>>>(initlv, levels);

  for (int it = 0; it < 12; ++it) {
    // scale of the previous iteration's accumulation is fused into prep (apply=1)
    prep_kernel<<<24576, 128, 0, stream>>>(levels, pos, levels_bf, levels_pos, invn,
                                           it > 0 ? 1 : 0);
    transpose_kernel<<<dim3(8, 4, 96), 256, 0, stream>>>(levels, levelsT);
    sim_kernel<<<dim3(2, 2, 96), 256, 0, stream>>>(levels_bf, invn, simattn);
    softmax_kernel<<<6144, 256, 0, stream>>>(simattn);
    pv_kernel<<<dim3(2, 4, 96), 256, 0, stream>>>(simattn, levelsT, levels);
    for (int g0 = 0; g0 < 11; g0 += gpp) {
      int gn = 11 - g0 < gpp ? 11 - g0 : gpp;
      ff1r_kernel<<<dim3(32, 16, gn), 256, 0, stream>>>(g0, gn, tokens, levels_bf, levels_pos,
                                                        w1_bf, bu_b1, td_b1, h);
      ff2r_kernel<<<dim3(32, 4, gn), 256, 0, stream>>>(g0, gn, h, w2_bf, bu_b2, td_b2, levels);
    }
  }
  scale_kernel<<<12288, 256, 0, stream>>>(levels);   // final contrib division
}

// Round 19
// 4635.938 us; speedup vs baseline: 2.5580x; 2.5580x over previous
//
#include <hip/hip_runtime.h>
#include <hip/hip_bf16.h>
#include <math.h>

typedef unsigned short ushort_t;

#define DEV __device__ __forceinline__

DEV float bf2f(ushort_t u) {
  return __uint_as_float(((unsigned int)u) << 16);
}
DEV ushort_t f2bf(float f) {
  unsigned int x = __float_as_uint(f);
  return (ushort_t)((x + 0x7FFFu + ((x >> 16) & 1u)) >> 16);
}

// Fast exact-gelu: Abramowitz-Stegun 7.1.26 erf approx, |err| <= 1.5e-7.
DEV float gelu_f(float x) {
  float z = fabsf(x) * 0.70710678118654752f;
  float t = __builtin_amdgcn_rcpf(1.0f + 0.3275911f * z);
  float p = t * (0.254829592f +
            t * (-0.284496736f +
            t * (1.421413741f +
            t * (-1.453152027f +
            t * 1.061405429f))));
  float e = 1.0f - p * __expf(-z * z);      // erf(|x|/sqrt(2))
  float s = (x >= 0.f) ? e : -e;
  return 0.5f * x * (1.0f + s);
}

using bf16x8 = __attribute__((ext_vector_type(8))) __bf16;
using f32x4  = __attribute__((ext_vector_type(4))) float;
using u32x4  = __attribute__((ext_vector_type(4))) unsigned int;

// ---- XCD-chunked block swizzle (T1, R15 measured -7us on ff1) ----
DEV int xcd_swz(int nwg) {
  int id = blockIdx.x + gridDim.x * (blockIdx.y + gridDim.y * blockIdx.z);
  return (id & 7) * (nwg >> 3) + (id >> 3);
}

// ============================================================================
// REG-STAGED 128x128 GEMM (T14, depth 1 — R12..R15/R17-proven at 4635-4637us).
// LAUNCH BOUNDS ARE LOAD-BEARING: (256,3) -> 76 VGPR, zero spill (proven).
//   (256,2)/default: allocator caps 96 VGPR -> staging spills (R11, 3x slow).
//   (256,4): allocator caps 64 VGPR -> staging spills (R18, 3x slow).
// Depth-2 register prefetch also spills (R16). DO NOT retune these.
// Single 32KB LDS, next tile in 32 VGPRs during MFMA; write-side XOR swizzle.
// C = A(MxK,rm,lda) * B^T, B(NxK,rm,ldb). K % 64 == 0.
// ============================================================================
template <typename F>
DEV void gemm_tileR(const ushort_t* A, int lda, const ushort_t* B, int ldb, int K, F&& epi) {
  __shared__ alignas(16) ushort_t As[128 * 64];
  __shared__ alignas(16) ushort_t Bs[128 * 64];
  int t = threadIdx.x;
  int lane = t & 63;
  int w = t >> 6;
  int wr = w >> 1, wc = w & 1;
  const int nk = K >> 6;
  f32x4 acc[4][4];
#pragma unroll
  for (int m = 0; m < 4; ++m)
#pragma unroll
    for (int n = 0; n < 4; ++n) acc[m][n] = (f32x4){0.f, 0.f, 0.f, 0.f};

  int aoff[4][2], boff[4][2];
#pragma unroll
  for (int m = 0; m < 4; ++m)
#pragma unroll
    for (int kk = 0; kk < 2; ++kk) {
      int ks = kk * 4 + (lane >> 4);
      aoff[m][kk] = (wr * 64 + m * 16 + (lane & 15)) * 64 + ((ks ^ (lane & 7)) * 8);
      boff[m][kk] = (wc * 64 + m * 16 + (lane & 15)) * 64 + ((ks ^ (lane & 7)) * 8);
    }

  u32x4 ra[4], rb[4];
  auto loadreg = [&](const ushort_t* g, int ld, u32x4* rr) {
#pragma unroll
    for (int r = 0; r < 4; ++r) {
      int chunk = r * 256 + t;
      rr[r] = *(const u32x4*)&g[(size_t)(chunk >> 3) * ld + (size_t)(chunk & 7) * 8];
    }
  };
  auto writelds = [&](ushort_t* lds, u32x4* rr) {
#pragma unroll
    for (int r = 0; r < 4; ++r) {
      int chunk = r * 256 + t;
      int row = chunk >> 3;
      int sl  = (chunk & 7) ^ (row & 7);          // write-side XOR swizzle
      *(u32x4*)&lds[(size_t)(row * 8 + sl) * 8] = rr[r];
    }
  };

  loadreg(A, lda, ra);
  loadreg(B, ldb, rb);

  for (int kt = 0; kt < nk; ++kt) {
    asm volatile("s_waitcnt vmcnt(0)" ::: "memory");   // tile-kt regs arrived
    __builtin_amdgcn_s_barrier();                      // prev reads done (LDS free)
    writelds(As, ra);
    writelds(Bs, rb);
    __builtin_amdgcn_s_barrier();                      // writes visible
    asm volatile("s_waitcnt lgkmcnt(0)" ::: "memory");
    __builtin_amdgcn_sched_barrier(0);
    if (kt + 1 < nk) {                                 // next tile flies under MFMA
      loadreg(A + (size_t)(kt + 1) * 64, lda, ra);
      loadreg(B + (size_t)(kt + 1) * 64, ldb, rb);
    }
#pragma unroll
    for (int kk = 0; kk < 2; ++kk) {
      bf16x8 af[4], bfr[4];
#pragma unroll
      for (int m = 0; m < 4; ++m) af[m] = *(const bf16x8*)&As[aoff[m][kk]];
#pragma unroll
      for (int n = 0; n < 4; ++n) bfr[n] = *(const bf16x8*)&Bs[boff[n][kk]];
      __builtin_amdgcn_s_setprio(1);
#pragma unroll
      for (int m = 0; m < 4; ++m)
#pragma unroll
        for (int n = 0; n < 4; ++n)
          acc[m][n] = __builtin_amdgcn_mfma_f32_16x16x32_bf16(af[m], bfr[n], acc[m][n], 0, 0, 0);
      __builtin_amdgcn_s_setprio(0);
    }
  }
  epi(wr, wc, lane, acc);
}

// ---- ff1 epilogue: paired-column packed store (w1 rows permuted by cvt_w1_kernel) ----
struct FF1Epi {
  const float* bias;
  ushort_t* out;
  int tn;
  DEV void operator()(int wr, int wc, int lane, f32x4 (&acc)[4][4]) const {
#pragma unroll
    for (int m = 0; m < 4; ++m)
#pragma unroll
      for (int q = 0; q < 2; ++q) {
        int col = wc * 64 + q * 32 + 2 * (lane & 15);      // original column (even)
        float b0 = bias[tn * 128 + col];
        float b1 = bias[tn * 128 + col + 1];
#pragma unroll
        for (int r = 0; r < 4; ++r) {
          int lr = wr * 64 + m * 16 + (lane >> 4) * 4 + r;
          float x0 = gelu_f(acc[m][2 * q][r] + b0);
          float x1 = gelu_f(acc[m][2 * q + 1][r] + b1);
          unsigned int pk = (unsigned int)f2bf(x0) | ((unsigned int)f2bf(x1) << 16);
          *(unsigned int*)&out[(size_t)lr * 2048 + col] = pk;
        }
      }
  }
};

// ---------------- FF layer 1: reg-staged tileR + XCD-chunked swizzle ----------------
__global__ __launch_bounds__(256, 3) void ff1r_kernel(
    int g0, int gn, const ushort_t* tokens, const ushort_t* levels_bf, const ushort_t* levels_pos,
    const ushort_t* w1_bf, const float* bu_b1, const float* td_b1, ushort_t* h) {
  int wid = xcd_swz(512 * gn);                 // grid = 32 x 16 x gn
  int tm = wid & 31, tn = (wid >> 5) & 15;
  int g = g0 + (wid >> 9);
  const ushort_t* A; int lda;
  if (g == 0)      { A = tokens     + (size_t)tm * 128 * 512;                              lda = 512;  }
  else if (g < 6)  { A = levels_bf  + (size_t)tm * 128 * 3072 + (size_t)(g - 1) * 512;     lda = 3072; }
  else             { A = levels_pos + (size_t)tm * 128 * 2560 + (size_t)(g - 6) * 512;     lda = 2560; }
  const ushort_t* W = w1_bf + (size_t)g * 2048 * 512 + (size_t)tn * 128 * 512;
  const float* bias = (g < 6) ? (bu_b1 + (size_t)g * 2048) : (td_b1 + (size_t)(g - 6) * 2048);
  ushort_t* out = h + ((size_t)(g - g0) * 4096 + (size_t)tm * 128) * 2048 + (size_t)tn * 128;
  FF1Epi epi{bias, out, tn};
  gemm_tileR(A, lda, W, 512, 512, epi);
}

// ---- ff2 epilogue: fused bias + f32 accumulate into levels ----
struct FF2Epi {
  const float* bias;
  float* levels;
  int tm, tn, l;
  DEV void operator()(int wr, int wc, int lane, f32x4 (&acc)[4][4]) const {
#pragma unroll
    for (int m = 0; m < 4; ++m)
#pragma unroll
      for (int n = 0; n < 4; ++n)
#pragma unroll
        for (int r = 0; r < 4; ++r) {
          int lr = wr * 64 + m * 16 + (lane >> 4) * 4 + r;
          int lc = wc * 64 + n * 16 + (lane & 15);
          int bn = tm * 128 + lr;
          int d  = tn * 128 + lc;
          size_t idx = ((size_t)bn * 6 + l) * 512 + d;
          levels[idx] += acc[m][n][r] + bias[d];
        }
  }
};

// ---------------- FF layer 2: reg-staged tileR + XCD-chunked swizzle ----------------
// RACE GUARD: one ff2 launch must never contain both group g and g+6 (both
// accumulate the SAME level l). Contiguous ranges of length <= 6 are safe.
__global__ __launch_bounds__(256, 3) void ff2r_kernel(
    int g0, int gn, const ushort_t* h, const ushort_t* w2_bf, const float* bu_b2,
    const float* td_b2, float* levels) {
  int wid = xcd_swz(128 * gn);                 // grid = 32 x 4 x gn
  int tm = wid & 31, tn = (wid >> 5) & 3;
  int g = g0 + (wid >> 7);
  const ushort_t* A = h + ((size_t)(g - g0) * 4096 + (size_t)tm * 128) * 2048;
  const ushort_t* W = w2_bf + (size_t)g * 512 * 2048 + (size_t)tn * 128 * 2048;
  int l = (g < 6) ? g : (g - 6);
  const float* bias = (g < 6) ? (bu_b2 + (size_t)g * 512) : (td_b2 + (size_t)(g - 6) * 512);
  FF2Epi epi{bias, levels, tm, tn, l};
  gemm_tileR(A, 2048, W, 2048, 2048, epi);
}

// ---- sim epilogue: inv-norm column scale + diag mask -> bf16 ----
struct SimEpi {
  const float* inv;
  ushort_t* out;
  int tm, tn;
  DEV void operator()(int wr, int wc, int lane, f32x4 (&acc)[4][4]) const {
#pragma unroll
    for (int m = 0; m < 4; ++m)
#pragma unroll
      for (int n = 0; n < 4; ++n)
#pragma unroll
        for (int r = 0; r < 4; ++r) {
          int lr = wr * 64 + m * 16 + (lane >> 4) * 4 + r;
          int lc = wc * 64 + n * 16 + (lane & 15);
          int i = tm * 128 + lr, j = tn * 128 + lc;
          float s = (i == j) ? -0.0005f : acc[m][n][r] * inv[j] * 0.044194173824159216f;
          out[(size_t)lr * 256 + lc] = f2bf(s);
        }
  }
};

// ---------------- SIM: tileR, fused inv-norm column scale + diag mask -> bf16 ----------
__global__ __launch_bounds__(256, 3) void sim_kernel(const ushort_t* levels_bf, const float* invn,
                                                     ushort_t* simattn) {
  int bl = blockIdx.z; int tm = blockIdx.x, tn = blockIdx.y;
  int b = bl / 6, l = bl % 6;
  const ushort_t* A = levels_bf + ((size_t)(b * 256 + tm * 128) * 6 + l) * 512;
  const ushort_t* B = levels_bf + ((size_t)(b * 256 + tn * 128) * 6 + l) * 512;
  const float* inv = invn + (size_t)bl * 256;
  ushort_t* out = simattn + ((size_t)bl * 256 + tm * 128) * 256 + (size_t)tn * 128;
  SimEpi epi{inv, out, tm, tn};
  gemm_tileR(A, 3072, B, 3072, 512, epi);
}

// ---- pv epilogue: f32 accumulate into levels ----
struct PvEpi {
  float* levels;
  int b, l, tm, tn;
  DEV void operator()(int wr, int wc, int lane, f32x4 (&acc)[4][4]) const {
#pragma unroll
    for (int m = 0; m < 4; ++m)
#pragma unroll
      for (int n = 0; n < 4; ++n)
#pragma unroll
        for (int r = 0; r < 4; ++r) {
          int lr = wr * 64 + m * 16 + (lane >> 4) * 4 + r;
          int lc = wc * 64 + n * 16 + (lane & 15);
          int nn = tm * 128 + lr;
          int d  = tn * 128 + lc;
          size_t idx = (((size_t)b * 256 + nn) * 6 + l) * 512 + d;
          levels[idx] += acc[m][n][r];
        }
  }
};

// ---------------- PV: tileR; levels += attn * levels_snapshot (f32) ----------------
__global__ __launch_bounds__(256, 3) void pv_kernel(const ushort_t* attn, const ushort_t* levelsT,
                                                    float* levels) {
  int bl = blockIdx.z; int tm = blockIdx.x, tn = blockIdx.y;
  int b = bl / 6, l = bl % 6;
  const ushort_t* A = attn + (size_t)bl * 256 * 256 + (size_t)tm * 128 * 256;
  const ushort_t* B = levelsT + ((size_t)bl * 512 + (size_t)tn * 128) * 256;
  PvEpi epi{levels, b, l, tm, tn};
  gemm_tileR(A, 256, B, 256, 256, epi);
}

// ---------------- softmax: one WAVE per 256-wide row (shuffle-reduce, no barriers) --------------
__global__ __launch_bounds__(256) void softmax_kernel(ushort_t* simattn) {
  int row = blockIdx.x * 4 + (threadIdx.x >> 6);
  int lane = threadIdx.x & 63;
  ushort_t* p = simattn + (size_t)row * 256 + lane * 4;
  ushort4 u = *(const ushort4*)p;
  float x0 = bf2f(u.x), x1 = bf2f(u.y), x2 = bf2f(u.z), x3 = bf2f(u.w);
  float mx = fmaxf(fmaxf(x0, x1), fmaxf(x2, x3));
#pragma unroll
  for (int off = 32; off > 0; off >>= 1) mx = fmaxf(mx, __shfl_xor(mx, off));
  float e0 = __expf(x0 - mx), e1 = __expf(x1 - mx), e2 = __expf(x2 - mx), e3 = __expf(x3 - mx);
  float s = e0 + e1 + e2 + e3;
#pragma unroll
  for (int off = 32; off > 0; off >>= 1) s += __shfl_xor(s, off);
  float r = __builtin_amdgcn_rcpf(s);
  u.x = f2bf(e0 * r); u.y = f2bf(e1 * r); u.z = f2bf(e2 * r); u.w = f2bf(e3 * r);
  *(ushort4*)p = u;
}

// ---- prep (+fused contrib scale): levels -> scaled levels, levels_bf, levels_pos, inv-norms ----
__global__ __launch_bounds__(128) void prep_kernel(float* levels, const float* pos_emb,
                                                   ushort_t* levels_bf, ushort_t* levels_pos,
                                                   float* invn, int apply) {
  int bid = blockIdx.x;           // (b*256+n)*6 + l
  int l = bid % 6;
  int bn = bid / 6;
  int n = bn & 255, b = bn >> 8;
  int t = threadIdx.x;
  float4 lv = *(const float4*)&levels[(size_t)bid * 512 + t * 4];
  if (apply) {
    float rc = (l == 5) ? (1.0f / 3.0f) : 0.25f;
    lv.x *= rc; lv.y *= rc; lv.z *= rc; lv.w *= rc;
    *(float4*)&levels[(size_t)bid * 512 + t * 4] = lv;   // write back scaled state
  }
  float ss = lv.x * lv.x + lv.y * lv.y + lv.z * lv.z + lv.w * lv.w;
#pragma unroll
  for (int off = 32; off > 0; off >>= 1) ss += __shfl_down(ss, off);
  __shared__ float s2[2];
  if ((t & 63) == 0) s2[t >> 6] = ss;
  __syncthreads();
  if (t == 0) {
    float tot = s2[0] + s2[1];
    invn[(size_t)(b * 6 + l) * 256 + n] = 1.0f / fmaxf(sqrtf(tot), 1e-12f);
  }
  ushort4 o;
  o.x = f2bf(lv.x); o.y = f2bf(lv.y); o.z = f2bf(lv.z); o.w = f2bf(lv.w);
  *(ushort4*)&levels_bf[(size_t)bid * 512 + t * 4] = o;
  if (l >= 1) {
    float4 pu = *(const float4*)&pos_emb[(size_t)n * 512 + t * 4];
    ushort4 op;
    op.x = f2bf(lv.x + pu.x);
    op.y = f2bf(lv.y + pu.y);
    op.z = f2bf(lv.z + pu.z);
    op.w = f2bf(lv.w + pu.w);
    *(ushort4*)&levels_pos[((size_t)bn * 5 + (l - 1)) * 512 + t * 4] = op;
  }
}

// ---------------- transpose: levels f32 (b,n,l,d) -> levelsT bf16 (b,l,d,n) ----------------
__global__ __launch_bounds__(256) void transpose_kernel(const float* levels, ushort_t* levelsT) {
  int bl = blockIdx.z; int b = bl / 6, l = bl % 6;
  int n0 = blockIdx.y * 64, d0 = blockIdx.x * 64;
  __shared__ ushort_t tile[64][72];
  int t = threadIdx.x;
#pragma unroll
  for (int rr = 0; rr < 2; ++rr) {
    int c = t + rr * 256;
    int r = c >> 3, c8 = (c & 7) * 8;
    const float* src = &levels[(((size_t)(b * 256 + n0 + r)) * 6 + l) * 512 + d0 + c8];
    float4 v0 = *(const float4*)src;
    float4 v1 = *(const float4*)(src + 4);
    tile[r][c8 + 0] = f2bf(v0.x); tile[r][c8 + 1] = f2bf(v0.y);
    tile[r][c8 + 2] = f2bf(v0.z); tile[r][c8 + 3] = f2bf(v0.w);
    tile[r][c8 + 4] = f2bf(v1.x); tile[r][c8 + 5] = f2bf(v1.y);
    tile[r][c8 + 6] = f2bf(v1.z); tile[r][c8 + 7] = f2bf(v1.w);
  }
  __syncthreads();
#pragma unroll
  for (int rr = 0; rr < 2; ++rr) {
    int c = t + rr * 256;
    int dr = c >> 3, n8 = (c & 7) * 8;
    ushort4 o0, o1;
    o0.x = tile[n8 + 0][dr]; o0.y = tile[n8 + 1][dr]; o0.z = tile[n8 + 2][dr]; o0.w = tile[n8 + 3][dr];
    o1.x = tile[n8 + 4][dr]; o1.y = tile[n8 + 5][dr]; o1.z = tile[n8 + 6][dr]; o1.w = tile[n8 + 7][dr];
    ushort_t* dst = &levelsT[((size_t)bl * 512 + d0 + dr) * 256 + n0 + n8];
    *(ushort4*)dst = o0;
    *(ushort4*)(dst + 4) = o1;
  }
}

// ---------------- patch embed: img(f32) -> tokens bf16 (4096 x 512) ----------------
__global__ __launch_bounds__(256) void tokens_kernel(const float* img, const float* ttw,
                                                     const float* ttb, ushort_t* tokens) {
  int token = blockIdx.x;
  int b = token >> 8, n = token & 255;
  int ph = n >> 4, pw = n & 15;
  __shared__ float patch[196];
  int t = threadIdx.x;
  if (t < 196) {
    int r = t / 14, cc = t % 14;
    patch[t] = img[(size_t)b * 50176 + (size_t)(ph * 14 + r) * 224 + pw * 14 + cc];
  }
  __syncthreads();
  float a0 = ttb[t];
  float a1 = ttb[t + 256];
  for (int k = 0; k < 196; ++k) {
    float p = patch[k];
    a0 += p * ttw[(size_t)k * 512 + t];
    a1 += p * ttw[(size_t)k * 512 + t + 256];
  }
  tokens[(size_t)token * 512 + t]       = f2bf(a0);
  tokens[(size_t)token * 512 + t + 256] = f2bf(a1);
}

// ---------------- init: broadcast init_levels(f32) -> levels f32 (d_out) ----------------
__global__ void init_kernel(const float* init_levels, float* levels) {
  size_t i4 = (size_t)blockIdx.x * 256 + threadIdx.x;
  size_t e0 = i4 * 4;
  int idx = (int)(e0 % 3072);
  *(float4*)&levels[e0] = *(const float4*)&init_levels[idx];
}

// ---------------- scale: levels *= 1/contrib[l], in place (final iteration only) ----------------
__global__ void scale_kernel(float* levels) {
  size_t i4 = (size_t)blockIdx.x * 256 + threadIdx.x;
  size_t e0 = i4 * 4;
  int l = (int)((e0 >> 9) % 6);
  float rc = (l == 5) ? (1.0f / 3.0f) : 0.25f;
  float4 a = *(const float4*)&levels[e0];
  float4 o = {a.x * rc, a.y * rc, a.z * rc, a.w * rc};
  *(float4*)&levels[e0] = o;
}

// ---------------- cvt: f32 -> bf16, 4 elems/thread (plain, for w2) ----------------
__global__ void cvt_kernel(const float* src, ushort_t* dst, int n4) {
  int i = blockIdx.x * 256 + threadIdx.x;
  if (i >= n4) return;
  float4 v = ((const float4*)src)[i];
  ushort4 o;
  o.x = f2bf(v.x); o.y = f2bf(v.y); o.z = f2bf(v.z); o.w = f2bf(v.w);
  ((ushort4*)dst)[i] = o;
}

// ---- cvt for w1: f32 -> bf16 with ROW PERMUTATION within 32-row groups ----
// staged row p = (r & ~31) | ((r&1)<<4) | ((r&31)>>1)  (rows = w1 output cols, 512-wide)
__global__ void cvt_w1_kernel(const float* src, ushort_t* dst, int nrows) {
  int i = blockIdx.x * 256 + threadIdx.x;          // one float4 (4 cols) per thread
  if (i >= nrows * 128) return;
  int row = i >> 7, k4 = (i & 127) * 4;
  int grp = row >> 11, rr = row & 2047;            // 2048 rows per group
  int p = (rr & ~31) | ((rr & 1) << 4) | ((rr & 31) >> 1);
  float4 v = *(const float4*)&src[(size_t)row * 512 + k4];
  ushort4 o;
  o.x = f2bf(v.x); o.y = f2bf(v.y); o.z = f2bf(v.z); o.w = f2bf(v.w);
  *(ushort4*)&dst[((size_t)(grp << 11) + p) * 512 + k4] = o;
}

extern "C" void kernel_launch(void* const* d_in, const int* in_sizes, int n_in,
                              void* d_out, int out_size, void* d_ws, size_t ws_size,
                              hipStream_t stream) {
  const float* img    = (const float*)d_in[0];
  const float* ttw    = (const float*)d_in[1];
  const float* ttb    = (const float*)d_in[2];
  const float* pos    = (const float*)d_in[3];
  const float* initlv = (const float*)d_in[4];
  const float* bu_w1  = (const float*)d_in[5];
  const float* bu_b1  = (const float*)d_in[6];
  const float* bu_w2  = (const float*)d_in[7];
  const float* bu_b2  = (const float*)d_in[8];
  const float* td_w1  = (const float*)d_in[9];
  const float* td_b1  = (const float*)d_in[10];
  const float* td_w2  = (const float*)d_in[11];
  const float* td_b2  = (const float*)d_in[12];

  float* levels = (float*)d_out;   // (b,n,6,512) f32 state lives in d_out

  const size_t HB = 16777216ull;   // bytes per h group (4096x2048 bf16)

  char* p = (char*)d_ws;
  auto alloc = [&](size_t bytes) { char* r = p; p += (bytes + 255) & ~(size_t)255; return r; };
  float*    invn       = (float*)alloc(24576ull * 4);
  ushort_t* tokens     = (ushort_t*)alloc(2097152ull * 2);
  ushort_t* levels_bf  = (ushort_t*)alloc(12582912ull * 2);
  ushort_t* levels_pos = (ushort_t*)alloc(10485760ull * 2);
  ushort_t* levelsT    = (ushort_t*)alloc(12582912ull * 2);
  ushort_t* simattn    = (ushort_t*)alloc(6291456ull * 2);
  ushort_t* w1_bf      = (ushort_t*)alloc(11534336ull * 2);
  ushort_t* w2_bf      = (ushort_t*)alloc(11534336ull * 2);
  size_t used = (size_t)(p - (char*)d_ws);
  if (used + HB > ws_size) return;                 // can't fit even 1-group h
  int gpp = (int)((ws_size - used) / HB);          // groups per FF pass
  if (gpp > 6) gpp = 6;                            // <=6 contiguous: no g/g+6 race
  ushort_t* h = (ushort_t*)alloc((size_t)gpp * HB);

  cvt_w1_kernel<<<6144, 256, 0, stream>>>(bu_w1, w1_bf, 12288);
  cvt_w1_kernel<<<5120, 256, 0, stream>>>(td_w1, w1_bf + 6291456ull, 10240);
  cvt_kernel<<<6144, 256, 0, stream>>>(bu_w2, w2_bf, 1572864);
  cvt_kernel<<<5120, 256, 0, stream>>>(td_w2, w2_bf + 6291456ull, 1310720);
  tokens_kernel<<<4096, 256, 0, stream>>>(img, ttw, ttb, tokens);
  init_kernel<<<12288, 256, 0, stream>>>(initlv, levels);

  for (int it = 0; it < 12; ++it) {
    // scale of the previous iteration's accumulation is fused into prep (apply=1)
    prep_kernel<<<24576, 128, 0, stream>>>(levels, pos, levels_bf, levels_pos, invn,
                                           it > 0 ? 1 : 0);
    transpose_kernel<<<dim3(8, 4, 96), 256, 0, stream>>>(levels, levelsT);
    sim_kernel<<<dim3(2, 2, 96), 256, 0, stream>>>(levels_bf, invn, simattn);
    softmax_kernel<<<6144, 256, 0, stream>>>(simattn);
    pv_kernel<<<dim3(2, 4, 96), 256, 0, stream>>>(simattn, levelsT, levels);
    for (int g0 = 0; g0 < 11; g0 += gpp) {
      int gn = 11 - g0 < gpp ? 11 - g0 : gpp;
      ff1r_kernel<<<dim3(32, 16, gn), 256, 0, stream>>>(g0, gn, tokens, levels_bf, levels_pos,
                                                        w1_bf, bu_b1, td_b1, h);
      ff2r_kernel<<<dim3(32, 4, gn), 256, 0, stream>>>(g0, gn, h, w2_bf, bu_b2, td_b2, levels);
    }
  }
  scale_kernel<<<12288, 256, 0, stream>>>(levels);   // final contrib division
}

// Round 20
// 4606.878 us; speedup vs baseline: 2.5742x; 1.0063x over previous
//
#include <hip/hip_runtime.h>
#include <hip/hip_bf16.h>
#include <math.h>

typedef unsigned short ushort_t;

#define DEV __device__ __forceinline__

DEV float bf2f(ushort_t u) {
  return __uint_as_float(((unsigned int)u) << 16);
}
DEV ushort_t f2bf(float f) {
  unsigned int x = __float_as_uint(f);
  return (ushort_t)((x + 0x7FFFu + ((x >> 16) & 1u)) >> 16);
}

// Fast exact-gelu: Abramowitz-Stegun 7.1.26 erf approx, |err| <= 1.5e-7.
DEV float gelu_f(float x) {
  float z = fabsf(x) * 0.70710678118654752f;
  float t = __builtin_amdgcn_rcpf(1.0f + 0.3275911f * z);
  float p = t * (0.254829592f +
            t * (-0.284496736f +
            t * (1.421413741f +
            t * (-1.453152027f +
            t * 1.061405429f))));
  float e = 1.0f - p * __expf(-z * z);      // erf(|x|/sqrt(2))
  float s = (x >= 0.f) ? e : -e;
  return 0.5f * x * (1.0f + s);
}

using bf16x8 = __attribute__((ext_vector_type(8))) __bf16;
using f32x4  = __attribute__((ext_vector_type(4))) float;
using u32x4  = __attribute__((ext_vector_type(4))) unsigned int;

// ---- XCD-chunked block swizzle (T1, R15 measured -7us on ff1) ----
DEV int xcd_swz(int nwg) {
  int id = blockIdx.x + gridDim.x * (blockIdx.y + gridDim.y * blockIdx.z);
  return (id & 7) * (nwg >> 3) + (id >> 3);
}

// ============================================================================
// REG-STAGED 128x128 GEMM (T14, depth 1 — R12..R15/R17/R19-proven at ~4636us).
// LAUNCH BOUNDS ARE LOAD-BEARING: (256,3) -> 76 VGPR, zero spill (proven).
//   (256,2)/default: allocator caps 96 VGPR -> staging spills (R11, 3x slow).
//   (256,4): allocator caps 64 VGPR -> staging spills (R18, 3x slow).
// Depth-2 register prefetch also spills (R16). DO NOT retune these.
// Single 32KB LDS, next tile in 32 VGPRs during MFMA; write-side XOR swizzle.
// C = A(MxK,rm,lda) * B^T, B(NxK,rm,ldb). K % 64 == 0.
// ============================================================================
template <typename F>
DEV void gemm_tileR(const ushort_t* A, int lda, const ushort_t* B, int ldb, int K, F&& epi) {
  __shared__ alignas(16) ushort_t As[128 * 64];
  __shared__ alignas(16) ushort_t Bs[128 * 64];
  int t = threadIdx.x;
  int lane = t & 63;
  int w = t >> 6;
  int wr = w >> 1, wc = w & 1;
  const int nk = K >> 6;
  f32x4 acc[4][4];
#pragma unroll
  for (int m = 0; m < 4; ++m)
#pragma unroll
    for (int n = 0; n < 4; ++n) acc[m][n] = (f32x4){0.f, 0.f, 0.f, 0.f};

  int aoff[4][2], boff[4][2];
#pragma unroll
  for (int m = 0; m < 4; ++m)
#pragma unroll
    for (int kk = 0; kk < 2; ++kk) {
      int ks = kk * 4 + (lane >> 4);
      aoff[m][kk] = (wr * 64 + m * 16 + (lane & 15)) * 64 + ((ks ^ (lane & 7)) * 8);
      boff[m][kk] = (wc * 64 + m * 16 + (lane & 15)) * 64 + ((ks ^ (lane & 7)) * 8);
    }

  u32x4 ra[4], rb[4];
  auto loadreg = [&](const ushort_t* g, int ld, u32x4* rr) {
#pragma unroll
    for (int r = 0; r < 4; ++r) {
      int chunk = r * 256 + t;
      rr[r] = *(const u32x4*)&g[(size_t)(chunk >> 3) * ld + (size_t)(chunk & 7) * 8];
    }
  };
  auto writelds = [&](ushort_t* lds, u32x4* rr) {
#pragma unroll
    for (int r = 0; r < 4; ++r) {
      int chunk = r * 256 + t;
      int row = chunk >> 3;
      int sl  = (chunk & 7) ^ (row & 7);          // write-side XOR swizzle
      *(u32x4*)&lds[(size_t)(row * 8 + sl) * 8] = rr[r];
    }
  };

  loadreg(A, lda, ra);
  loadreg(B, ldb, rb);

  for (int kt = 0; kt < nk; ++kt) {
    asm volatile("s_waitcnt vmcnt(0)" ::: "memory");   // tile-kt regs arrived
    __builtin_amdgcn_s_barrier();                      // prev reads done (LDS free)
    writelds(As, ra);
    writelds(Bs, rb);
    __builtin_amdgcn_s_barrier();                      // writes visible
    asm volatile("s_waitcnt lgkmcnt(0)" ::: "memory");
    __builtin_amdgcn_sched_barrier(0);
    if (kt + 1 < nk) {                                 // next tile flies under MFMA
      loadreg(A + (size_t)(kt + 1) * 64, lda, ra);
      loadreg(B + (size_t)(kt + 1) * 64, ldb, rb);
    }
#pragma unroll
    for (int kk = 0; kk < 2; ++kk) {
      bf16x8 af[4], bfr[4];
#pragma unroll
      for (int m = 0; m < 4; ++m) af[m] = *(const bf16x8*)&As[aoff[m][kk]];
#pragma unroll
      for (int n = 0; n < 4; ++n) bfr[n] = *(const bf16x8*)&Bs[boff[n][kk]];
      __builtin_amdgcn_s_setprio(1);
#pragma unroll
      for (int m = 0; m < 4; ++m)
#pragma unroll
        for (int n = 0; n < 4; ++n)
          acc[m][n] = __builtin_amdgcn_mfma_f32_16x16x32_bf16(af[m], bfr[n], acc[m][n], 0, 0, 0);
      __builtin_amdgcn_s_setprio(0);
    }
  }
  epi(wr, wc, lane, acc);
}

// ---- ff1 epilogue: paired-column packed store (w1 rows permuted by cvt_w1_kernel) ----
struct FF1Epi {
  const float* bias;
  ushort_t* out;
  int tn;
  DEV void operator()(int wr, int wc, int lane, f32x4 (&acc)[4][4]) const {
#pragma unroll
    for (int m = 0; m < 4; ++m)
#pragma unroll
      for (int q = 0; q < 2; ++q) {
        int col = wc * 64 + q * 32 + 2 * (lane & 15);      // original column (even)
        float b0 = bias[tn * 128 + col];
        float b1 = bias[tn * 128 + col + 1];
#pragma unroll
        for (int r = 0; r < 4; ++r) {
          int lr = wr * 64 + m * 16 + (lane >> 4) * 4 + r;
          float x0 = gelu_f(acc[m][2 * q][r] + b0);
          float x1 = gelu_f(acc[m][2 * q + 1][r] + b1);
          unsigned int pk = (unsigned int)f2bf(x0) | ((unsigned int)f2bf(x1) << 16);
          *(unsigned int*)&out[(size_t)lr * 2048 + col] = pk;
        }
      }
  }
};

// ---------------- FF layer 1: reg-staged tileR + XCD-chunked swizzle ----------------
__global__ __launch_bounds__(256, 3) void ff1r_kernel(
    int g0, int gn, const ushort_t* tokens, const ushort_t* levels_bf, const ushort_t* levels_pos,
    const ushort_t* w1_bf, const float* bu_b1, const float* td_b1, ushort_t* h) {
  int wid = xcd_swz(512 * gn);                 // grid = 32 x 16 x gn
  int tm = wid & 31, tn = (wid >> 5) & 15;
  int g = g0 + (wid >> 9);
  const ushort_t* A; int lda;
  if (g == 0)      { A = tokens     + (size_t)tm * 128 * 512;                              lda = 512;  }
  else if (g < 6)  { A = levels_bf  + (size_t)tm * 128 * 3072 + (size_t)(g - 1) * 512;     lda = 3072; }
  else             { A = levels_pos + (size_t)tm * 128 * 2560 + (size_t)(g - 6) * 512;     lda = 2560; }
  const ushort_t* W = w1_bf + (size_t)g * 2048 * 512 + (size_t)tn * 128 * 512;
  const float* bias = (g < 6) ? (bu_b1 + (size_t)g * 2048) : (td_b1 + (size_t)(g - 6) * 2048);
  ushort_t* out = h + ((size_t)(g - g0) * 4096 + (size_t)tm * 128) * 2048 + (size_t)tn * 128;
  FF1Epi epi{bias, out, tn};
  gemm_tileR(A, lda, W, 512, 512, epi);
}

// ---- ff2 epilogue: fused bias + f32 accumulate into levels ----
struct FF2Epi {
  const float* bias;
  float* levels;
  int tm, tn, l;
  DEV void operator()(int wr, int wc, int lane, f32x4 (&acc)[4][4]) const {
#pragma unroll
    for (int m = 0; m < 4; ++m)
#pragma unroll
      for (int n = 0; n < 4; ++n)
#pragma unroll
        for (int r = 0; r < 4; ++r) {
          int lr = wr * 64 + m * 16 + (lane >> 4) * 4 + r;
          int lc = wc * 64 + n * 16 + (lane & 15);
          int bn = tm * 128 + lr;
          int d  = tn * 128 + lc;
          size_t idx = ((size_t)bn * 6 + l) * 512 + d;
          levels[idx] += acc[m][n][r] + bias[d];
        }
  }
};

// ---------------- FF layer 2: reg-staged tileR + XCD-chunked swizzle ----------------
// RACE GUARD: one ff2 launch must never contain both group g and g+6 (both
// accumulate the SAME level l). Contiguous ranges of length <= 6 are safe.
__global__ __launch_bounds__(256, 3) void ff2r_kernel(
    int g0, int gn, const ushort_t* h, const ushort_t* w2_bf, const float* bu_b2,
    const float* td_b2, float* levels) {
  int wid = xcd_swz(128 * gn);                 // grid = 32 x 4 x gn
  int tm = wid & 31, tn = (wid >> 5) & 3;
  int g = g0 + (wid >> 7);
  const ushort_t* A = h + ((size_t)(g - g0) * 4096 + (size_t)tm * 128) * 2048;
  const ushort_t* W = w2_bf + (size_t)g * 512 * 2048 + (size_t)tn * 128 * 2048;
  int l = (g < 6) ? g : (g - 6);
  const float* bias = (g < 6) ? (bu_b2 + (size_t)g * 512) : (td_b2 + (size_t)(g - 6) * 512);
  FF2Epi epi{bias, levels, tm, tn, l};
  gemm_tileR(A, 2048, W, 2048, 2048, epi);
}

// ---- sim epilogue: inv-norm column scale + diag mask -> bf16 ----
struct SimEpi {
  const float* inv;
  ushort_t* out;
  int tm, tn;
  DEV void operator()(int wr, int wc, int lane, f32x4 (&acc)[4][4]) const {
#pragma unroll
    for (int m = 0; m < 4; ++m)
#pragma unroll
      for (int n = 0; n < 4; ++n)
#pragma unroll
        for (int r = 0; r < 4; ++r) {
          int lr = wr * 64 + m * 16 + (lane >> 4) * 4 + r;
          int lc = wc * 64 + n * 16 + (lane & 15);
          int i = tm * 128 + lr, j = tn * 128 + lc;
          float s = (i == j) ? -0.0005f : acc[m][n][r] * inv[j] * 0.044194173824159216f;
          out[(size_t)lr * 256 + lc] = f2bf(s);
        }
  }
};

// ---------------- SIM: tileR, fused inv-norm column scale + diag mask -> bf16 ----------
__global__ __launch_bounds__(256, 3) void sim_kernel(const ushort_t* levels_bf, const float* invn,
                                                     ushort_t* simattn) {
  int bl = blockIdx.z; int tm = blockIdx.x, tn = blockIdx.y;
  int b = bl / 6, l = bl % 6;
  const ushort_t* A = levels_bf + ((size_t)(b * 256 + tm * 128) * 6 + l) * 512;
  const ushort_t* B = levels_bf + ((size_t)(b * 256 + tn * 128) * 6 + l) * 512;
  const float* inv = invn + (size_t)bl * 256;
  ushort_t* out = simattn + ((size_t)bl * 256 + tm * 128) * 256 + (size_t)tn * 128;
  SimEpi epi{inv, out, tm, tn};
  gemm_tileR(A, 3072, B, 3072, 512, epi);
}

// ---- pv epilogue: f32 accumulate into levels ----
struct PvEpi {
  float* levels;
  int b, l, tm, tn;
  DEV void operator()(int wr, int wc, int lane, f32x4 (&acc)[4][4]) const {
#pragma unroll
    for (int m = 0; m < 4; ++m)
#pragma unroll
      for (int n = 0; n < 4; ++n)
#pragma unroll
        for (int r = 0; r < 4; ++r) {
          int lr = wr * 64 + m * 16 + (lane >> 4) * 4 + r;
          int lc = wc * 64 + n * 16 + (lane & 15);
          int nn = tm * 128 + lr;
          int d  = tn * 128 + lc;
          size_t idx = (((size_t)b * 256 + nn) * 6 + l) * 512 + d;
          levels[idx] += acc[m][n][r];
        }
  }
};

// ---------------- PV: tileR; levels += attn * levels_snapshot (f32) ----------------
__global__ __launch_bounds__(256, 3) void pv_kernel(const ushort_t* attn, const ushort_t* levelsT,
                                                    float* levels) {
  int bl = blockIdx.z; int tm = blockIdx.x, tn = blockIdx.y;
  int b = bl / 6, l = bl % 6;
  const ushort_t* A = attn + (size_t)bl * 256 * 256 + (size_t)tm * 128 * 256;
  const ushort_t* B = levelsT + ((size_t)bl * 512 + (size_t)tn * 128) * 256;
  PvEpi epi{levels, b, l, tm, tn};
  gemm_tileR(A, 256, B, 256, 256, epi);
}

// ---------------- softmax: one WAVE per 256-wide row (shuffle-reduce, no barriers) --------------
__global__ __launch_bounds__(256) void softmax_kernel(ushort_t* simattn) {
  int row = blockIdx.x * 4 + (threadIdx.x >> 6);
  int lane = threadIdx.x & 63;
  ushort_t* p = simattn + (size_t)row * 256 + lane * 4;
  ushort4 u = *(const ushort4*)p;
  float x0 = bf2f(u.x), x1 = bf2f(u.y), x2 = bf2f(u.z), x3 = bf2f(u.w);
  float mx = fmaxf(fmaxf(x0, x1), fmaxf(x2, x3));
#pragma unroll
  for (int off = 32; off > 0; off >>= 1) mx = fmaxf(mx, __shfl_xor(mx, off));
  float e0 = __expf(x0 - mx), e1 = __expf(x1 - mx), e2 = __expf(x2 - mx), e3 = __expf(x3 - mx);
  float s = e0 + e1 + e2 + e3;
#pragma unroll
  for (int off = 32; off > 0; off >>= 1) s += __shfl_xor(s, off);
  float r = __builtin_amdgcn_rcpf(s);
  u.x = f2bf(e0 * r); u.y = f2bf(e1 * r); u.z = f2bf(e2 * r); u.w = f2bf(e3 * r);
  *(ushort4*)p = u;
}

// ---- prep (+fused contrib scale): levels -> scaled levels, levels_bf, levels_pos, inv-norms ----
__global__ __launch_bounds__(128) void prep_kernel(float* levels, const float* pos_emb,
                                                   ushort_t* levels_bf, ushort_t* levels_pos,
                                                   float* invn, int apply) {
  int bid = blockIdx.x;           // (b*256+n)*6 + l
  int l = bid % 6;
  int bn = bid / 6;
  int n = bn & 255, b = bn >> 8;
  int t = threadIdx.x;
  float4 lv = *(const float4*)&levels[(size_t)bid * 512 + t * 4];
  if (apply) {
    float rc = (l == 5) ? (1.0f / 3.0f) : 0.25f;
    lv.x *= rc; lv.y *= rc; lv.z *= rc; lv.w *= rc;
    *(float4*)&levels[(size_t)bid * 512 + t * 4] = lv;   // write back scaled state
  }
  float ss = lv.x * lv.x + lv.y * lv.y + lv.z * lv.z + lv.w * lv.w;
#pragma unroll
  for (int off = 32; off > 0; off >>= 1) ss += __shfl_down(ss, off);
  __shared__ float s2[2];
  if ((t & 63) == 0) s2[t >> 6] = ss;
  __syncthreads();
  if (t == 0) {
    float tot = s2[0] + s2[1];
    invn[(size_t)(b * 6 + l) * 256 + n] = 1.0f / fmaxf(sqrtf(tot), 1e-12f);
  }
  ushort4 o;
  o.x = f2bf(lv.x); o.y = f2bf(lv.y); o.z = f2bf(lv.z); o.w = f2bf(lv.w);
  *(ushort4*)&levels_bf[(size_t)bid * 512 + t * 4] = o;
  if (l >= 1) {
    float4 pu = *(const float4*)&pos_emb[(size_t)n * 512 + t * 4];
    ushort4 op;
    op.x = f2bf(lv.x + pu.x);
    op.y = f2bf(lv.y + pu.y);
    op.z = f2bf(lv.z + pu.z);
    op.w = f2bf(lv.w + pu.w);
    *(ushort4*)&levels_pos[((size_t)bn * 5 + (l - 1)) * 512 + t * 4] = op;
  }
}

// ---- transpose: levels_bf bf16 (b,n,l,d) -> levelsT bf16 (b,l,d,n) ----
// Reads the bf16 copy prep already produced (bit-identical to converting the
// f32 source; halves this kernel's read traffic vs reading levels f32).
__global__ __launch_bounds__(256) void transpose_kernel(const ushort_t* levels_bf,
                                                        ushort_t* levelsT) {
  int bl = blockIdx.z; int b = bl / 6, l = bl % 6;
  int n0 = blockIdx.y * 64, d0 = blockIdx.x * 64;
  __shared__ ushort_t tile[64][72];
  int t = threadIdx.x;
#pragma unroll
  for (int rr = 0; rr < 2; ++rr) {
    int c = t + rr * 256;
    int r = c >> 3, c8 = (c & 7) * 8;
    const ushort_t* src = &levels_bf[(((size_t)(b * 256 + n0 + r)) * 6 + l) * 512 + d0 + c8];
    ushort4 v0 = *(const ushort4*)src;
    ushort4 v1 = *(const ushort4*)(src + 4);
    tile[r][c8 + 0] = v0.x; tile[r][c8 + 1] = v0.y;
    tile[r][c8 + 2] = v0.z; tile[r][c8 + 3] = v0.w;
    tile[r][c8 + 4] = v1.x; tile[r][c8 + 5] = v1.y;
    tile[r][c8 + 6] = v1.z; tile[r][c8 + 7] = v1.w;
  }
  __syncthreads();
#pragma unroll
  for (int rr = 0; rr < 2; ++rr) {
    int c = t + rr * 256;
    int dr = c >> 3, n8 = (c & 7) * 8;
    ushort4 o0, o1;
    o0.x = tile[n8 + 0][dr]; o0.y = tile[n8 + 1][dr]; o0.z = tile[n8 + 2][dr]; o0.w = tile[n8 + 3][dr];
    o1.x = tile[n8 + 4][dr]; o1.y = tile[n8 + 5][dr]; o1.z = tile[n8 + 6][dr]; o1.w = tile[n8 + 7][dr];
    ushort_t* dst = &levelsT[((size_t)bl * 512 + d0 + dr) * 256 + n0 + n8];
    *(ushort4*)dst = o0;
    *(ushort4*)(dst + 4) = o1;
  }
}

// ---------------- patch embed: img(f32) -> tokens bf16 (4096 x 512) ----------------
__global__ __launch_bounds__(256) void tokens_kernel(const float* img, const float* ttw,
                                                     const float* ttb, ushort_t* tokens) {
  int token = blockIdx.x;
  int b = token >> 8, n = token & 255;
  int ph = n >> 4, pw = n & 15;
  __shared__ float patch[196];
  int t = threadIdx.x;
  if (t < 196) {
    int r = t / 14, cc = t % 14;
    patch[t] = img[(size_t)b * 50176 + (size_t)(ph * 14 + r) * 224 + pw * 14 + cc];
  }
  __syncthreads();
  float a0 = ttb[t];
  float a1 = ttb[t + 256];
  for (int k = 0; k < 196; ++k) {
    float p = patch[k];
    a0 += p * ttw[(size_t)k * 512 + t];
    a1 += p * ttw[(size_t)k * 512 + t + 256];
  }
  tokens[(size_t)token * 512 + t]       = f2bf(a0);
  tokens[(size_t)token * 512 + t + 256] = f2bf(a1);
}

// ---------------- init: broadcast init_levels(f32) -> levels f32 (d_out) ----------------
__global__ void init_kernel(const float* init_levels, float* levels) {
  size_t i4 = (size_t)blockIdx.x * 256 + threadIdx.x;
  size_t e0 = i4 * 4;
  int idx = (int)(e0 % 3072);
  *(float4*)&levels[e0] = *(const float4*)&init_levels[idx];
}

// ---------------- scale: levels *= 1/contrib[l], in place (final iteration only) ----------------
__global__ void scale_kernel(float* levels) {
  size_t i4 = (size_t)blockIdx.x * 256 + threadIdx.x;
  size_t e0 = i4 * 4;
  int l = (int)((e0 >> 9) % 6);
  float rc = (l == 5) ? (1.0f / 3.0f) : 0.25f;
  float4 a = *(const float4*)&levels[e0];
  float4 o = {a.x * rc, a.y * rc, a.z * rc, a.w * rc};
  *(float4*)&levels[e0] = o;
}

// ---------------- cvt: f32 -> bf16, 4 elems/thread (plain, for w2) ----------------
__global__ void cvt_kernel(const float* src, ushort_t* dst, int n4) {
  int i = blockIdx.x * 256 + threadIdx.x;
  if (i >= n4) return;
  float4 v = ((const float4*)src)[i];
  ushort4 o;
  o.x = f2bf(v.x); o.y = f2bf(v.y); o.z = f2bf(v.z); o.w = f2bf(v.w);
  ((ushort4*)dst)[i] = o;
}

// ---- cvt for w1: f32 -> bf16 with ROW PERMUTATION within 32-row groups ----
// staged row p = (r & ~31) | ((r&1)<<4) | ((r&31)>>1)  (rows = w1 output cols, 512-wide)
__global__ void cvt_w1_kernel(const float* src, ushort_t* dst, int nrows) {
  int i = blockIdx.x * 256 + threadIdx.x;          // one float4 (4 cols) per thread
  if (i >= nrows * 128) return;
  int row = i >> 7, k4 = (i & 127) * 4;
  int grp = row >> 11, rr = row & 2047;            // 2048 rows per group
  int p = (rr & ~31) | ((rr & 1) << 4) | ((rr & 31) >> 1);
  float4 v = *(const float4*)&src[(size_t)row * 512 + k4];
  ushort4 o;
  o.x = f2bf(v.x); o.y = f2bf(v.y); o.z = f2bf(v.z); o.w = f2bf(v.w);
  *(ushort4*)&dst[((size_t)(grp << 11) + p) * 512 + k4] = o;
}

extern "C" void kernel_launch(void* const* d_in, const int* in_sizes, int n_in,
                              void* d_out, int out_size, void* d_ws, size_t ws_size,
                              hipStream_t stream) {
  const float* img    = (const float*)d_in[0];
  const float* ttw    = (const float*)d_in[1];
  const float* ttb    = (const float*)d_in[2];
  const float* pos    = (const float*)d_in[3];
  const float* initlv = (const float*)d_in[4];
  const float* bu_w1  = (const float*)d_in[5];
  const float* bu_b1  = (const float*)d_in[6];
  const float* bu_w2  = (const float*)d_in[7];
  const float* bu_b2  = (const float*)d_in[8];
  const float* td_w1  = (const float*)d_in[9];
  const float* td_b1  = (const float*)d_in[10];
  const float* td_w2  = (const float*)d_in[11];
  const float* td_b2  = (const float*)d_in[12];

  float* levels = (float*)d_out;   // (b,n,6,512) f32 state lives in d_out

  const size_t HB = 16777216ull;   // bytes per h group (4096x2048 bf16)

  char* p = (char*)d_ws;
  auto alloc = [&](size_t bytes) { char* r = p; p += (bytes + 255) & ~(size_t)255; return r; };
  float*    invn       = (float*)alloc(24576ull * 4);
  ushort_t* tokens     = (ushort_t*)alloc(2097152ull * 2);
  ushort_t* levels_bf  = (ushort_t*)alloc(12582912ull * 2);
  ushort_t* levels_pos = (ushort_t*)alloc(10485760ull * 2);
  ushort_t* levelsT    = (ushort_t*)alloc(12582912ull * 2);
  ushort_t* simattn    = (ushort_t*)alloc(6291456ull * 2);
  ushort_t* w1_bf      = (ushort_t*)alloc(11534336ull * 2);
  ushort_t* w2_bf      = (ushort_t*)alloc(11534336ull * 2);
  size_t used = (size_t)(p - (char*)d_ws);
  if (used + HB > ws_size) return;                 // can't fit even 1-group h
  int gpp = (int)((ws_size - used) / HB);          // groups per FF pass
  if (gpp > 6) gpp = 6;                            // <=6 contiguous: no g/g+6 race
  ushort_t* h = (ushort_t*)alloc((size_t)gpp * HB);

  cvt_w1_kernel<<<6144, 256, 0, stream>>>(bu_w1, w1_bf, 12288);
  cvt_w1_kernel<<<5120, 256, 0, stream>>>(td_w1, w1_bf + 6291456ull, 10240);
  cvt_kernel<<<6144, 256, 0, stream>>>(bu_w2, w2_bf, 1572864);
  cvt_kernel<<<5120, 256, 0, stream>>>(td_w2, w2_bf + 6291456ull, 1310720);
  tokens_kernel<<<4096, 256, 0, stream>>>(img, ttw, ttb, tokens);
  init_kernel<<<12288, 256, 0, stream>>>(initlv, levels);

  for (int it = 0; it < 12; ++it) {
    // scale of the previous iteration's accumulation is fused into prep (apply=1)
    prep_kernel<<<24576, 128, 0, stream>>>(levels, pos, levels_bf, levels_pos, invn,
                                           it > 0 ? 1 : 0);
    transpose_kernel<<<dim3(8, 4, 96), 256, 0, stream>>>(levels_bf, levelsT);
    sim_kernel<<<dim3(2, 2, 96), 256, 0, stream>>>(levels_bf, invn, simattn);
    softmax_kernel<<<6144, 256, 0, stream>>>(simattn);
    pv_kernel<<<dim3(2, 4, 96), 256, 0, stream>>>(simattn, levelsT, levels);
    for (int g0 = 0; g0 < 11; g0 += gpp) {
      int gn = 11 - g0 < gpp ? 11 - g0 : gpp;
      ff1r_kernel<<<dim3(32, 16, gn), 256, 0, stream>>>(g0, gn, tokens, levels_bf, levels_pos,
                                                        w1_bf, bu_b1, td_b1, h);
      ff2r_kernel<<<dim3(32, 4, gn), 256, 0, stream>>>(g0, gn, h, w2_bf, bu_b2, td_b2, levels);
    }
  }
  scale_kernel<<<12288, 256, 0, stream>>>(levels);   // final contrib division
}